// Round 1
// baseline (246.478 us; speedup 1.0000x reference)
//
#include <hip/hip_runtime.h>
#include <stdint.h>

#define S_LEN 4096
#define D_DIM 2048
#define NT 16
#define TD 128
#define KW 4
#define CTX 640
#define HID 256

typedef __bf16 bf16_t;
typedef __bf16 bf16x8 __attribute__((ext_vector_type(8)));
typedef __bf16 bf16x4 __attribute__((ext_vector_type(4)));
typedef float f32x4 __attribute__((ext_vector_type(4)));
typedef unsigned int u32;
typedef u32 __attribute__((address_space(1))) gu32;
typedef u32 __attribute__((address_space(3))) lu32;

__device__ __forceinline__ void gload_lds16(const void* g, void* l) {
    __builtin_amdgcn_global_load_lds((const gu32*)g, (lu32*)l, 16, 0, 0);
}

// ---------------- Kernel 1: LayerNorm + x_norm(bf16) + per-block tile-sum partials
__global__ __launch_bounds__(256) void k_ln(const float* __restrict__ x,
        const float* __restrict__ gamma, const float* __restrict__ beta,
        bf16_t* __restrict__ xn, float* __restrict__ partial)
{
    __shared__ float wsum[4][2048];
    const int tid = threadIdx.x, lane = tid & 63, w = tid >> 6;
    const int blk = blockIdx.x;                    // 1024 blocks, 8 rows each (2/wave)
    float cs[8][4];
#pragma unroll
    for (int j = 0; j < 8; ++j) { cs[j][0]=0.f; cs[j][1]=0.f; cs[j][2]=0.f; cs[j][3]=0.f; }
#pragma unroll
    for (int i = 0; i < 2; ++i) {
        const int r = blk*8 + w*2 + i;
        const float4* xr = (const float4*)(x + (size_t)r * D_DIM);
        float4 v[8]; float s = 0.f, ss = 0.f;
#pragma unroll
        for (int j = 0; j < 8; ++j) {
            v[j] = xr[j*64 + lane];
            s  += v[j].x + v[j].y + v[j].z + v[j].w;
            ss += v[j].x*v[j].x + v[j].y*v[j].y + v[j].z*v[j].z + v[j].w*v[j].w;
        }
#pragma unroll
        for (int off = 32; off; off >>= 1) { s += __shfl_xor(s, off); ss += __shfl_xor(ss, off); }
        const float mean = s * (1.f/2048.f);
        const float var  = ss * (1.f/2048.f) - mean*mean;
        const float rstd = rsqrtf(var + 1e-5f);
#pragma unroll
        for (int j = 0; j < 8; ++j) {
            const int c4 = j*64 + lane;
            const float4 g4 = *(const float4*)(gamma + c4*4);
            const float4 b4 = *(const float4*)(beta  + c4*4);
            float n0 = (v[j].x - mean)*rstd*g4.x + b4.x;
            float n1 = (v[j].y - mean)*rstd*g4.y + b4.y;
            float n2 = (v[j].z - mean)*rstd*g4.z + b4.z;
            float n3 = (v[j].w - mean)*rstd*g4.w + b4.w;
            cs[j][0]+=n0; cs[j][1]+=n1; cs[j][2]+=n2; cs[j][3]+=n3;
            bf16x4 o; o[0]=(bf16_t)n0; o[1]=(bf16_t)n1; o[2]=(bf16_t)n2; o[3]=(bf16_t)n3;
            *(bf16x4*)(xn + (size_t)r*D_DIM + c4*4) = o;
        }
    }
#pragma unroll
    for (int j = 0; j < 8; ++j) {
        float4 t4; t4.x=cs[j][0]; t4.y=cs[j][1]; t4.z=cs[j][2]; t4.w=cs[j][3];
        *(float4*)&wsum[w][(j*64+lane)*4] = t4;
    }
    __syncthreads();
#pragma unroll
    for (int p = 0; p < 2; ++p) {
        const int c4 = p*256 + tid;  // 0..511 (float4 index)
        float4 a0 = *(const float4*)&wsum[0][c4*4];
        float4 a1 = *(const float4*)&wsum[1][c4*4];
        float4 a2 = *(const float4*)&wsum[2][c4*4];
        float4 a3 = *(const float4*)&wsum[3][c4*4];
        float4 r4; r4.x=a0.x+a1.x+a2.x+a3.x; r4.y=a0.y+a1.y+a2.y+a3.y;
        r4.z=a0.z+a1.z+a2.z+a3.z; r4.w=a0.w+a1.w+a2.w+a3.w;
        *(float4*)(partial + (size_t)blk*D_DIM + c4*4) = r4;
    }
}

// ---------------- Kernel 2: reduce partials -> tile_repr [B][2048]
__global__ void k_reduce(const float* __restrict__ partial, float* __restrict__ repr) {
    const int g = blockIdx.x * 256 + threadIdx.x;  // 4096
    const int b = g >> 11, d = g & 2047;
    const float* p = partial + (size_t)b * 512 * D_DIM + d;
    float s = 0.f;
    for (int i = 0; i < 512; ++i) s += p[(size_t)i * D_DIM];
    repr[g] = s * (1.f / 4096.f);
}

// ---------------- Kernel 3: routing (q,k,l2norm,scores,top-4) -> routes [B][T][K]
__global__ __launch_bounds__(256) void k_route(const float* __restrict__ repr,
        const float* __restrict__ Wq, const float* __restrict__ bq,
        const float* __restrict__ Wk, const float* __restrict__ bk,
        int* __restrict__ routes)
{
    __shared__ float sr[2][2048];
    __shared__ float sq[2][16][128];
    __shared__ float sk[2][16][128];
    __shared__ float sc[2][16][16];
    __shared__ float rn[2][2][16];
    const int tid = threadIdx.x;
    for (int i = tid; i < 4096; i += 256) sr[i >> 11][i & 2047] = repr[i];
    __syncthreads();
    for (int o = tid; o < 4096; o += 256) {
        const int b = o >> 11, rem = o & 2047, t = rem >> 7, d = rem & 127;
        const float* rp = sr[b] + t*128;
        const float* wq = Wq + d*128;
        const float* wk = Wk + d*128;
        float aq = bq[d], ak = bk[d];
        for (int c = 0; c < 128; ++c) { aq += rp[c]*wq[c]; ak += rp[c]*wk[c]; }
        sq[b][t][d] = aq; sk[b][t][d] = ak;
    }
    __syncthreads();
    if (tid < 64) {
        const int b = tid >> 5, which = (tid >> 4) & 1, t = tid & 15;
        const float* v = which ? sk[b][t] : sq[b][t];
        float ss = 0.f;
        for (int c = 0; c < 128; ++c) ss += v[c]*v[c];
        rn[b][which][t] = 1.f / fmaxf(sqrtf(ss), 1e-12f);
    }
    __syncthreads();
    for (int e = tid; e < 512; e += 256) {
        const int b = e >> 8, t = (e >> 4) & 15, u = e & 15;
        float s = 0.f;
        for (int c = 0; c < 128; ++c) s += sq[b][t][c]*sk[b][u][c];
        s *= rn[b][0][t] * rn[b][1][u];
        sc[b][t][u] = (u == t) ? -1e9f : s;
    }
    __syncthreads();
    if (tid < 32) {
        const int b = tid >> 4, t = tid & 15;
        unsigned taken = 0;
        for (int kk = 0; kk < 4; ++kk) {
            float bv = -3.0e38f; int bu = 0;
            for (int u = 0; u < 16; ++u) {
                if ((taken >> u) & 1u) continue;
                const float v = sc[b][t][u];
                if (v > bv) { bv = v; bu = u; }   // strict > = lax.top_k tie-break
            }
            taken |= (1u << bu);
            routes[(b*16 + t)*4 + kk] = bu;
        }
    }
}

// ---------------- Kernel 4: pre-tile + pre-swizzle W1/W2 into bf16 LDS images
// LDS slot L holds logical element at (byte L) ^ ((row&7)<<4)  [rows of 128B]
__global__ void k_prep(const float* __restrict__ W1, const float* __restrict__ W2,
                       bf16_t* __restrict__ W1t, bf16_t* __restrict__ W2t) {
    const int g = blockIdx.x * 256 + threadIdx.x;
    if (g < 10*256*64) {
        const int ks = g >> 14, rem = g & 16383, n = rem >> 6, kk = rem & 63;
        const int kkl = ((kk << 1) ^ ((n & 7) << 4)) >> 1;
        W1t[g] = (bf16_t)W1[n*CTX + ks*64 + kkl];
    } else if (g < 10*256*64 + 4*128*64) {
        const int gg = g - 10*256*64;
        const int ks = gg >> 13, rem = gg & 8191, n = rem >> 6, kk = rem & 63;
        const int kkl = ((kk << 1) ^ ((n & 7) << 4)) >> 1;
        W2t[gg] = (bf16_t)W2[n*HID + ks*64 + kkl];
    }
}

// ---------------- Kernel 5: fused gather + MLP (2 GEMMs, bf16 MFMA) + residual
// BM=128 rows (8 s x 16 t), 4 waves, N1=256 split 64/wave, N2=128 split 32/wave.
__global__ __launch_bounds__(256, 2) void k_mlp(
    const float* __restrict__ x, const bf16_t* __restrict__ xn,
    const bf16_t* __restrict__ W1t, const bf16_t* __restrict__ W2t,
    const float* __restrict__ b1, const float* __restrict__ b2,
    const int* __restrict__ routes, float* __restrict__ out)
{
    __shared__ char lds[65536];
    char* combL = lds;              // [128][64] bf16, 16KB       (GEMM1)
    char* w1L   = lds + 16384;      // [256][64] bf16, 32KB       (GEMM1)
    char* hL    = lds;              // [128][128] bf16, 32KB      (half of h, phased)
    char* w2L   = lds + 49152;      // [128][64] bf16, 16KB       (GEMM2)
    int*  srcT  = (int*)(lds + 49152);  // [16][5], alive only during GEMM1

    const int tid = threadIdx.x, lane = tid & 63, w = tid >> 6;
    const int blk = blockIdx.x;
    const int b  = blk >> 9;
    const int s0 = (blk & 511) * 8;

    if (tid < 80) {
        const int t = tid / 5, j = tid % 5;
        srcT[tid] = (j == 0) ? t : routes[(b*NT + t)*KW + (j-1)];
    }
    __syncthreads();

    // staging-lane constants: chunk q=it*4+w covers m = it*32 + w*8 + (lane>>3)
    const int sub = w*8 + (lane >> 3);          // 0..31
    const int tt  = sub & 15;                   // tile index t of this lane's m-rows
    const int hi  = sub >> 4;                   // 0/1
    const size_t rowc = ((size_t)(b*S_LEN + s0 + hi)) * D_DIM;
    const int kkE = ((lane & 7) ^ ((lane >> 3) & 7)) * 8;  // source-side swizzle

    f32x4 acc[4][8];
#pragma unroll
    for (int i = 0; i < 4; ++i)
#pragma unroll
        for (int j = 0; j < 8; ++j) acc[i][j] = (f32x4){0.f,0.f,0.f,0.f};

    const int nbase = w * 64;

    for (int ks = 0; ks < 10; ++ks) {
        const int src = srcT[tt*5 + (ks >> 1)];
        const size_t cbase = rowc + (size_t)src*TD + (size_t)((ks & 1)*64 + kkE);
#pragma unroll
        for (int it = 0; it < 4; ++it)
            gload_lds16(xn + cbase + (size_t)it*2*D_DIM, combL + (it*4 + w)*1024);
        const bf16_t* w1g = W1t + ks*16384 + lane*8;
#pragma unroll
        for (int it = 0; it < 8; ++it) {
            const int q = it*4 + w;
            gload_lds16(w1g + q*512, w1L + q*1024);
        }
        asm volatile("s_waitcnt vmcnt(0)");
        __syncthreads();
#pragma unroll
        for (int kk = 0; kk < 2; ++kk) {
            const int kb = (kk*32 + ((lane >> 4) * 8)) * 2;
            bf16x8 af[4], bfr[8];
#pragma unroll
            for (int nf = 0; nf < 4; ++nf) {
                const int n = nbase + nf*16 + (lane & 15);
                af[nf] = *(const bf16x8*)(w1L + n*128 + (kb ^ ((n & 7) << 4)));
            }
#pragma unroll
            for (int mf = 0; mf < 8; ++mf) {
                const int m = mf*16 + (lane & 15);
                bfr[mf] = *(const bf16x8*)(combL + m*128 + (kb ^ ((m & 7) << 4)));
            }
#pragma unroll
            for (int nf = 0; nf < 4; ++nf)
#pragma unroll
                for (int mf = 0; mf < 8; ++mf)
                    acc[nf][mf] = __builtin_amdgcn_mfma_f32_16x16x32_bf16(
                        af[nf], bfr[mf], acc[nf][mf], 0, 0, 0);
        }
        __syncthreads();
    }

    // epilogue 1: bias + gelu (tanh approx) -> packed bf16 regs
    bf16x4 hreg[4][8];
#pragma unroll
    for (int nf = 0; nf < 4; ++nf) {
        const int n0 = nbase + nf*16 + ((lane >> 4) * 4);
        const float4 b1v = *(const float4*)(b1 + n0);
#pragma unroll
        for (int mf = 0; mf < 8; ++mf) {
#pragma unroll
            for (int r = 0; r < 4; ++r) {
                const float z = acc[nf][mf][r] + ((const float*)&b1v)[r];
                const float u = z + 0.044715f * z * z * z;
                const float gl = z / (1.f + __expf(-1.5957691216f * u));
                hreg[nf][mf][r] = (bf16_t)gl;
            }
        }
    }

    // phase A: waves 0,1 write h columns 0..127 into hL
    const int colb = (nbase & 127) + ((lane >> 4) * 4);
    if (w < 2) {
#pragma unroll
        for (int nf = 0; nf < 4; ++nf) {
            const int cb2 = (colb + nf*16) * 2;
#pragma unroll
            for (int mf = 0; mf < 8; ++mf) {
                const int m = mf*16 + (lane & 15);
                *(bf16x4*)(hL + m*256 + (cb2 ^ ((m & 7) << 4))) = hreg[nf][mf];
            }
        }
    }

    // GEMM2: out = h @ W2^T, K=256 in two phases of 128
    f32x4 acc2[2][8];
#pragma unroll
    for (int i = 0; i < 2; ++i)
#pragma unroll
        for (int j = 0; j < 8; ++j) acc2[i][j] = (f32x4){0.f,0.f,0.f,0.f};

    for (int ks2 = 0; ks2 < 4; ++ks2) {
        if (ks2 == 2) {
            if (w >= 2) {   // phase B: waves 2,3 write h columns 128..255
#pragma unroll
                for (int nf = 0; nf < 4; ++nf) {
                    const int cb2 = (colb + nf*16) * 2;
#pragma unroll
                    for (int mf = 0; mf < 8; ++mf) {
                        const int m = mf*16 + (lane & 15);
                        *(bf16x4*)(hL + m*256 + (cb2 ^ ((m & 7) << 4))) = hreg[nf][mf];
                    }
                }
            }
            __syncthreads();
        }
        const bf16_t* w2g = W2t + ks2*8192 + lane*8;
#pragma unroll
        for (int it = 0; it < 4; ++it) {
            const int q = it*4 + w;
            gload_lds16(w2g + q*512, w2L + q*1024);
        }
        asm volatile("s_waitcnt vmcnt(0)");
        __syncthreads();
#pragma unroll
        for (int kk = 0; kk < 2; ++kk) {
            const int kbW = (kk*32 + ((lane >> 4) * 8)) * 2;
            const int kbH = (((ks2 & 1) * 64) + kk*32 + ((lane >> 4) * 8)) * 2;
            bf16x8 ah[8], bw2[2];
#pragma unroll
            for (int mf = 0; mf < 8; ++mf) {
                const int m = mf*16 + (lane & 15);
                ah[mf] = *(const bf16x8*)(hL + m*256 + (kbH ^ ((m & 7) << 4)));
            }
#pragma unroll
            for (int nf = 0; nf < 2; ++nf) {
                const int n2 = w*32 + nf*16 + (lane & 15);
                bw2[nf] = *(const bf16x8*)(w2L + n2*128 + (kbW ^ ((n2 & 7) << 4)));
            }
#pragma unroll
            for (int nf = 0; nf < 2; ++nf)
#pragma unroll
                for (int mf = 0; mf < 8; ++mf)
                    acc2[nf][mf] = __builtin_amdgcn_mfma_f32_16x16x32_bf16(
                        ah[mf], bw2[nf], acc2[nf][mf], 0, 0, 0);
        }
        __syncthreads();
    }

    // epilogue 2: + b2 + residual x
#pragma unroll
    for (int nf = 0; nf < 2; ++nf) {
        const int n2 = w*32 + nf*16 + (lane & 15);
        const float b2v = b2[n2];
#pragma unroll
        for (int mf = 0; mf < 8; ++mf) {
            const int mb = mf*16 + ((lane >> 4) * 4);
#pragma unroll
            for (int r = 0; r < 4; ++r) {
                const int m = mb + r;
                const int s = s0 + (m >> 4);
                const int t = m & 15;
                const size_t o = ((size_t)(b*S_LEN + s))*D_DIM + t*TD + n2;
                out[o] = x[o] + acc2[nf][mf][r] + b2v;
            }
        }
    }
}

extern "C" void kernel_launch(void* const* d_in, const int* in_sizes, int n_in,
                              void* d_out, int out_size, void* d_ws, size_t ws_size,
                              hipStream_t stream) {
    const float* x     = (const float*)d_in[0];
    const float* gamma = (const float*)d_in[1];
    const float* beta  = (const float*)d_in[2];
    const float* Wq    = (const float*)d_in[3];
    const float* bq    = (const float*)d_in[4];
    const float* Wk    = (const float*)d_in[5];
    const float* bk    = (const float*)d_in[6];
    const float* W1    = (const float*)d_in[7];
    const float* b1    = (const float*)d_in[8];
    const float* W2    = (const float*)d_in[9];
    const float* b2    = (const float*)d_in[10];
    float* out = (float*)d_out;

    char* ws = (char*)d_ws;
    bf16_t* xn      = (bf16_t*)ws;                   // 33,554,432 B
    float*  partial = (float*) (ws + 33554432);      //  8,388,608 B
    float*  repr    = (float*) (ws + 41943040);      //     16,384 B
    int*    routes  = (int*)   (ws + 41959424);      //        512 B
    bf16_t* W1t     = (bf16_t*)(ws + 41959936);      //    327,680 B
    bf16_t* W2t     = (bf16_t*)(ws + 42287616);      //     65,536 B

    k_ln<<<1024, 256, 0, stream>>>(x, gamma, beta, xn, partial);
    k_reduce<<<16, 256, 0, stream>>>(partial, repr);
    k_route<<<1, 256, 0, stream>>>(repr, Wq, bq, Wk, bk, routes);
    k_prep<<<768, 256, 0, stream>>>(W1, W2, W1t, W2t);
    k_mlp<<<1024, 256, 0, stream>>>(x, xn, W1t, W2t, b1, b2, routes, out);
}

// Round 3
// 126.877 us; speedup vs baseline: 1.9426x; 1.9426x over previous
//
#include <hip/hip_runtime.h>
#include <stdint.h>

#define S_LEN 4096
#define D_DIM 2048
#define NT 16
#define TD 128
#define KW 4
#define CTX 640
#define HID 256

typedef __bf16 bf16_t;
typedef __bf16 bf16x8 __attribute__((ext_vector_type(8)));
typedef __bf16 bf16x4 __attribute__((ext_vector_type(4)));
typedef float f32x4 __attribute__((ext_vector_type(4)));
typedef unsigned int u32;
typedef u32 __attribute__((address_space(1))) gu32;
typedef u32 __attribute__((address_space(3))) lu32;

__device__ __forceinline__ void gload_lds16(const void* g, void* l) {
    __builtin_amdgcn_global_load_lds((const gu32*)g, (lu32*)l, 16, 0, 0);
}

// ---------------- Kernel 1: LayerNorm + x_norm(bf16) + per-block tile-sum partials
// 512 blocks x 16 rows each (4 rows/wave). partial: [512][2048] f32.
__global__ __launch_bounds__(256) void k_ln(const float* __restrict__ x,
        const float* __restrict__ gamma, const float* __restrict__ beta,
        bf16_t* __restrict__ xn, float* __restrict__ partial)
{
    __shared__ float wsum[4][2048];
    const int tid = threadIdx.x, lane = tid & 63, w = tid >> 6;
    const int blk = blockIdx.x;
    float cs[8][4];
#pragma unroll
    for (int j = 0; j < 8; ++j) { cs[j][0]=0.f; cs[j][1]=0.f; cs[j][2]=0.f; cs[j][3]=0.f; }
#pragma unroll
    for (int i = 0; i < 4; ++i) {
        const int r = blk*16 + w*4 + i;
        const float4* xr = (const float4*)(x + (size_t)r * D_DIM);
        float4 v[8]; float s = 0.f, ss = 0.f;
#pragma unroll
        for (int j = 0; j < 8; ++j) {
            v[j] = xr[j*64 + lane];
            s  += v[j].x + v[j].y + v[j].z + v[j].w;
            ss += v[j].x*v[j].x + v[j].y*v[j].y + v[j].z*v[j].z + v[j].w*v[j].w;
        }
#pragma unroll
        for (int off = 32; off; off >>= 1) { s += __shfl_xor(s, off); ss += __shfl_xor(ss, off); }
        const float mean = s * (1.f/2048.f);
        const float var  = ss * (1.f/2048.f) - mean*mean;
        const float rstd = rsqrtf(var + 1e-5f);
#pragma unroll
        for (int j = 0; j < 8; ++j) {
            const int c4 = j*64 + lane;
            const float4 g4 = *(const float4*)(gamma + c4*4);
            const float4 b4 = *(const float4*)(beta  + c4*4);
            float n0 = (v[j].x - mean)*rstd*g4.x + b4.x;
            float n1 = (v[j].y - mean)*rstd*g4.y + b4.y;
            float n2 = (v[j].z - mean)*rstd*g4.z + b4.z;
            float n3 = (v[j].w - mean)*rstd*g4.w + b4.w;
            cs[j][0]+=n0; cs[j][1]+=n1; cs[j][2]+=n2; cs[j][3]+=n3;
            bf16x4 o; o[0]=(bf16_t)n0; o[1]=(bf16_t)n1; o[2]=(bf16_t)n2; o[3]=(bf16_t)n3;
            *(bf16x4*)(xn + (size_t)r*D_DIM + c4*4) = o;
        }
    }
#pragma unroll
    for (int j = 0; j < 8; ++j) {
        float4 t4; t4.x=cs[j][0]; t4.y=cs[j][1]; t4.z=cs[j][2]; t4.w=cs[j][3];
        *(float4*)&wsum[w][(j*64+lane)*4] = t4;
    }
    __syncthreads();
#pragma unroll
    for (int p = 0; p < 2; ++p) {
        const int c4 = p*256 + tid;  // 0..511 (float4 index)
        float4 a0 = *(const float4*)&wsum[0][c4*4];
        float4 a1 = *(const float4*)&wsum[1][c4*4];
        float4 a2 = *(const float4*)&wsum[2][c4*4];
        float4 a3 = *(const float4*)&wsum[3][c4*4];
        float4 r4; r4.x=a0.x+a1.x+a2.x+a3.x; r4.y=a0.y+a1.y+a2.y+a3.y;
        r4.z=a0.z+a1.z+a2.z+a3.z; r4.w=a0.w+a1.w+a2.w+a3.w;
        *(float4*)(partial + (size_t)blk*D_DIM + c4*4) = r4;
    }
}

// ---------------- Kernel 2a: partial[512][2048] -> partial2[64][2048]
__global__ __launch_bounds__(256) void k_red1(const float* __restrict__ partial,
                                              float* __restrict__ partial2) {
    const int g = blockIdx.x, tid = threadIdx.x;   // 64 blocks
#pragma unroll
    for (int p = 0; p < 2; ++p) {
        const int c4 = p*256 + tid;
        float4 s = {0.f,0.f,0.f,0.f};
#pragma unroll
        for (int r = 0; r < 8; ++r) {
            float4 v = *(const float4*)(partial + ((size_t)(g*8+r))*2048 + c4*4);
            s.x+=v.x; s.y+=v.y; s.z+=v.z; s.w+=v.w;
        }
        *(float4*)(partial2 + (size_t)g*2048 + c4*4) = s;
    }
}

// ---------------- Kernel 2b: partial2[64][2048] -> repr[2][2048] (mean over S)
__global__ __launch_bounds__(256) void k_red2(const float* __restrict__ partial2,
                                              float* __restrict__ repr) {
    const int g = blockIdx.x, tid = threadIdx.x;   // 16 blocks
    const int b = g >> 3, col = (g & 7)*256 + tid;
    float s = 0.f;
#pragma unroll 8
    for (int r = 0; r < 32; ++r) s += partial2[(size_t)(b*32+r)*2048 + col];
    repr[b*2048 + col] = s * (1.f/4096.f);
}

// ---------------- Kernel 3a: q/k projection + l2norm -> qkbuf[2(which)][2][16][128]
// 64 blocks: one per (b, t, which). 16 lanes per output dot, 8 dots/thread-group step.
__global__ __launch_bounds__(256) void k_qk(const float* __restrict__ repr,
        const float* __restrict__ Wq, const float* __restrict__ bq,
        const float* __restrict__ Wk, const float* __restrict__ bk,
        float* __restrict__ qkbuf)
{
    __shared__ float rrow[128];
    __shared__ float yrow[128];
    __shared__ float ssum[2];
    const int g = blockIdx.x;
    const int b = g >> 5, t = (g >> 1) & 15, which = g & 1;
    const float* W    = which ? Wk : Wq;
    const float* bias = which ? bk : bq;
    const int tid = threadIdx.x, lane = tid & 63, w = tid >> 6;
    if (tid < 32) *(float4*)&rrow[tid*4] = *(const float4*)(repr + b*2048 + t*128 + tid*4);
    __syncthreads();
    const int c0 = (lane & 15) * 8;
#pragma unroll
    for (int r = 0; r < 8; ++r) {
        const int d = r*16 + w*4 + (lane >> 4);   // covers 0..127
        const float4 w0 = *(const float4*)(W + d*128 + c0);
        const float4 w1 = *(const float4*)(W + d*128 + c0 + 4);
        float acc = w0.x*rrow[c0]   + w0.y*rrow[c0+1] + w0.z*rrow[c0+2] + w0.w*rrow[c0+3]
                  + w1.x*rrow[c0+4] + w1.y*rrow[c0+5] + w1.z*rrow[c0+6] + w1.w*rrow[c0+7];
#pragma unroll
        for (int off = 1; off <= 8; off <<= 1) acc += __shfl_xor(acc, off);
        if ((lane & 15) == 0) yrow[d] = acc + bias[d];
    }
    __syncthreads();
    if (tid < 128) {
        float v = yrow[tid];
        float sq = v * v;
#pragma unroll
        for (int off = 32; off; off >>= 1) sq += __shfl_xor(sq, off);
        if (lane == 0) ssum[tid >> 6] = sq;
    }
    __syncthreads();
    if (tid < 128) {
        const float rn = 1.f / fmaxf(sqrtf(ssum[0] + ssum[1]), 1e-12f);
        qkbuf[(which*32 + b*16 + t)*128 + tid] = yrow[tid] * rn;
    }
}

// ---------------- Kernel 3b: scores + top-4 -> routes [B][T][K]
__global__ __launch_bounds__(256) void k_score(const float* __restrict__ qkbuf,
                                               int* __restrict__ routes)
{
    __shared__ float qk_s[8192];      // [which(2)][b(2)][t(16)][128]
    __shared__ float sc[2][16][16];
    const int tid = threadIdx.x;
    for (int i = tid; i < 2048; i += 256)
        *(float4*)&qk_s[i*4] = *(const float4*)(qkbuf + i*4);
    __syncthreads();
#pragma unroll
    for (int p = 0; p < 2; ++p) {
        const int e = p*256 + tid;            // 0..511
        const int b = e >> 8, t = (e >> 4) & 15, u = e & 15;
        const float4* qr = (const float4*)&qk_s[(b*16 + t)*128];
        const float4* kr = (const float4*)&qk_s[(32 + b*16 + u)*128];
        float s = 0.f;
#pragma unroll
        for (int c = 0; c < 32; ++c) {
            float4 a = qr[c], bb = kr[c];
            s += a.x*bb.x + a.y*bb.y + a.z*bb.z + a.w*bb.w;
        }
        sc[b][t][u] = (u == t) ? -1e9f : s;
    }
    __syncthreads();
    if (tid < 32) {
        const int b = tid >> 4, t = tid & 15;
        unsigned taken = 0;
        for (int kk = 0; kk < 4; ++kk) {
            float bv = -3.0e38f; int bu = 0;
            for (int u = 0; u < 16; ++u) {
                if ((taken >> u) & 1u) continue;
                const float v = sc[b][t][u];
                if (v > bv) { bv = v; bu = u; }   // strict > = lax.top_k tie-break
            }
            taken |= (1u << bu);
            routes[(b*16 + t)*4 + kk] = bu;
        }
    }
}

// ---------------- Kernel 4: pre-tile + pre-swizzle W1/W2 into bf16 LDS images
// LDS slot L holds logical element at (byte L) ^ ((row&7)<<4)  [rows of 128B]
__global__ void k_prep(const float* __restrict__ W1, const float* __restrict__ W2,
                       bf16_t* __restrict__ W1t, bf16_t* __restrict__ W2t) {
    const int g = blockIdx.x * 256 + threadIdx.x;
    if (g < 10*256*64) {
        const int ks = g >> 14, rem = g & 16383, n = rem >> 6, kk = rem & 63;
        const int kkl = ((kk << 1) ^ ((n & 7) << 4)) >> 1;
        W1t[g] = (bf16_t)W1[n*CTX + ks*64 + kkl];
    } else if (g < 10*256*64 + 4*128*64) {
        const int gg = g - 10*256*64;
        const int ks = gg >> 13, rem = gg & 8191, n = rem >> 6, kk = rem & 63;
        const int kkl = ((kk << 1) ^ ((n & 7) << 4)) >> 1;
        W2t[gg] = (bf16_t)W2[n*HID + ks*64 + kkl];
    }
}

// ---------------- Kernel 5: fused gather + MLP (2 GEMMs, bf16 MFMA) + residual
// BM=128 rows (8 s x 16 t), 4 waves, N1=256 split 64/wave, N2=128 split 32/wave.
__global__ __launch_bounds__(256, 2) void k_mlp(
    const float* __restrict__ x, const bf16_t* __restrict__ xn,
    const bf16_t* __restrict__ W1t, const bf16_t* __restrict__ W2t,
    const float* __restrict__ b1, const float* __restrict__ b2,
    const int* __restrict__ routes, float* __restrict__ out)
{
    __shared__ char lds[65536];
    char* combL = lds;              // [128][64] bf16, 16KB       (GEMM1)
    char* w1L   = lds + 16384;      // [256][64] bf16, 32KB       (GEMM1)
    char* hL    = lds;              // [128][128] bf16, 32KB      (half of h, phased)
    char* w2L   = lds + 49152;      // [128][64] bf16, 16KB       (GEMM2)
    int*  srcT  = (int*)(lds + 49152);  // [16][5], alive only during GEMM1

    const int tid = threadIdx.x, lane = tid & 63, w = tid >> 6;
    const int blk = blockIdx.x;
    const int b  = blk >> 9;
    const int s0 = (blk & 511) * 8;

    if (tid < 80) {
        const int t = tid / 5, j = tid % 5;
        srcT[tid] = (j == 0) ? t : routes[(b*NT + t)*KW + (j-1)];
    }
    __syncthreads();

    // staging-lane constants: chunk q=it*4+w covers m = it*32 + w*8 + (lane>>3)
    const int sub = w*8 + (lane >> 3);          // 0..31
    const int tt  = sub & 15;                   // tile index t of this lane's m-rows
    const int hi  = sub >> 4;                   // 0/1
    const size_t rowc = ((size_t)(b*S_LEN + s0 + hi)) * D_DIM;
    const int kkE = ((lane & 7) ^ ((lane >> 3) & 7)) * 8;  // source-side swizzle

    f32x4 acc[4][8];
#pragma unroll
    for (int i = 0; i < 4; ++i)
#pragma unroll
        for (int j = 0; j < 8; ++j) acc[i][j] = (f32x4){0.f,0.f,0.f,0.f};

    const int nbase = w * 64;

    for (int ks = 0; ks < 10; ++ks) {
        const int src = srcT[tt*5 + (ks >> 1)];
        const size_t cbase = rowc + (size_t)src*TD + (size_t)((ks & 1)*64 + kkE);
#pragma unroll
        for (int it = 0; it < 4; ++it)
            gload_lds16(xn + cbase + (size_t)it*2*D_DIM, combL + (it*4 + w)*1024);
        const bf16_t* w1g = W1t + ks*16384 + lane*8;
#pragma unroll
        for (int it = 0; it < 8; ++it) {
            const int q = it*4 + w;
            gload_lds16(w1g + q*512, w1L + q*1024);
        }
        asm volatile("s_waitcnt vmcnt(0)");
        __syncthreads();
#pragma unroll
        for (int kk = 0; kk < 2; ++kk) {
            const int kb = (kk*32 + ((lane >> 4) * 8)) * 2;
            bf16x8 af[4], bfr[8];
#pragma unroll
            for (int nf = 0; nf < 4; ++nf) {
                const int n = nbase + nf*16 + (lane & 15);
                af[nf] = *(const bf16x8*)(w1L + n*128 + (kb ^ ((n & 7) << 4)));
            }
#pragma unroll
            for (int mf = 0; mf < 8; ++mf) {
                const int m = mf*16 + (lane & 15);
                bfr[mf] = *(const bf16x8*)(combL + m*128 + (kb ^ ((m & 7) << 4)));
            }
#pragma unroll
            for (int nf = 0; nf < 4; ++nf)
#pragma unroll
                for (int mf = 0; mf < 8; ++mf)
                    acc[nf][mf] = __builtin_amdgcn_mfma_f32_16x16x32_bf16(
                        af[nf], bfr[mf], acc[nf][mf], 0, 0, 0);
        }
        __syncthreads();
    }

    // epilogue 1: bias + gelu (tanh approx) -> packed bf16 regs
    bf16x4 hreg[4][8];
#pragma unroll
    for (int nf = 0; nf < 4; ++nf) {
        const int n0 = nbase + nf*16 + ((lane >> 4) * 4);
        const float4 b1v = *(const float4*)(b1 + n0);
#pragma unroll
        for (int mf = 0; mf < 8; ++mf) {
#pragma unroll
            for (int r = 0; r < 4; ++r) {
                const float z = acc[nf][mf][r] + ((const float*)&b1v)[r];
                const float u = z + 0.044715f * z * z * z;
                const float gl = z / (1.f + __expf(-1.5957691216f * u));
                hreg[nf][mf][r] = (bf16_t)gl;
            }
        }
    }

    // phase A: waves 0,1 write h columns 0..127 into hL
    const int colb = (nbase & 127) + ((lane >> 4) * 4);
    if (w < 2) {
#pragma unroll
        for (int nf = 0; nf < 4; ++nf) {
            const int cb2 = (colb + nf*16) * 2;
#pragma unroll
            for (int mf = 0; mf < 8; ++mf) {
                const int m = mf*16 + (lane & 15);
                *(bf16x4*)(hL + m*256 + (cb2 ^ ((m & 7) << 4))) = hreg[nf][mf];
            }
        }
    }

    // GEMM2: out = h @ W2^T, K=256 in two phases of 128
    f32x4 acc2[2][8];
#pragma unroll
    for (int i = 0; i < 2; ++i)
#pragma unroll
        for (int j = 0; j < 8; ++j) acc2[i][j] = (f32x4){0.f,0.f,0.f,0.f};

    for (int ks2 = 0; ks2 < 4; ++ks2) {
        if (ks2 == 2) {
            if (w >= 2) {   // phase B: waves 2,3 write h columns 128..255
#pragma unroll
                for (int nf = 0; nf < 4; ++nf) {
                    const int cb2 = (colb + nf*16) * 2;
#pragma unroll
                    for (int mf = 0; mf < 8; ++mf) {
                        const int m = mf*16 + (lane & 15);
                        *(bf16x4*)(hL + m*256 + (cb2 ^ ((m & 7) << 4))) = hreg[nf][mf];
                    }
                }
            }
            __syncthreads();
        }
        const bf16_t* w2g = W2t + ks2*8192 + lane*8;
#pragma unroll
        for (int it = 0; it < 4; ++it) {
            const int q = it*4 + w;
            gload_lds16(w2g + q*512, w2L + q*1024);
        }
        asm volatile("s_waitcnt vmcnt(0)");
        __syncthreads();
#pragma unroll
        for (int kk = 0; kk < 2; ++kk) {
            const int kbW = (kk*32 + ((lane >> 4) * 8)) * 2;
            const int kbH = (((ks2 & 1) * 64) + kk*32 + ((lane >> 4) * 8)) * 2;
            bf16x8 ah[8], bw2[2];
#pragma unroll
            for (int mf = 0; mf < 8; ++mf) {
                const int m = mf*16 + (lane & 15);
                ah[mf] = *(const bf16x8*)(hL + m*256 + (kbH ^ ((m & 7) << 4)));
            }
#pragma unroll
            for (int nf = 0; nf < 2; ++nf) {
                const int n2 = w*32 + nf*16 + (lane & 15);
                bw2[nf] = *(const bf16x8*)(w2L + n2*128 + (kbW ^ ((n2 & 7) << 4)));
            }
#pragma unroll
            for (int nf = 0; nf < 2; ++nf)
#pragma unroll
                for (int mf = 0; mf < 8; ++mf)
                    acc2[nf][mf] = __builtin_amdgcn_mfma_f32_16x16x32_bf16(
                        ah[mf], bw2[nf], acc2[nf][mf], 0, 0, 0);
        }
        __syncthreads();
    }

    // epilogue 2: + b2 + residual x
#pragma unroll
    for (int nf = 0; nf < 2; ++nf) {
        const int n2 = w*32 + nf*16 + (lane & 15);
        const float b2v = b2[n2];
#pragma unroll
        for (int mf = 0; mf < 8; ++mf) {
            const int mb = mf*16 + ((lane >> 4) * 4);
#pragma unroll
            for (int r = 0; r < 4; ++r) {
                const int m = mb + r;
                const int s = s0 + (m >> 4);
                const int t = m & 15;
                const size_t o = ((size_t)(b*S_LEN + s))*D_DIM + t*TD + n2;
                out[o] = x[o] + acc2[nf][mf][r] + b2v;
            }
        }
    }
}

extern "C" void kernel_launch(void* const* d_in, const int* in_sizes, int n_in,
                              void* d_out, int out_size, void* d_ws, size_t ws_size,
                              hipStream_t stream) {
    const float* x     = (const float*)d_in[0];
    const float* gamma = (const float*)d_in[1];
    const float* beta  = (const float*)d_in[2];
    const float* Wq    = (const float*)d_in[3];
    const float* bq    = (const float*)d_in[4];
    const float* Wk    = (const float*)d_in[5];
    const float* bk    = (const float*)d_in[6];
    const float* W1    = (const float*)d_in[7];
    const float* b1    = (const float*)d_in[8];
    const float* W2    = (const float*)d_in[9];
    const float* b2    = (const float*)d_in[10];
    float* out = (float*)d_out;

    char* ws = (char*)d_ws;
    bf16_t* xn       = (bf16_t*)ws;                   // 33,554,432 B
    float*  partial  = (float*) (ws + 33554432);      //  4,194,304 B [512][2048]
    float*  partial2 = (float*) (ws + 37748736);      //    524,288 B [64][2048]
    float*  repr     = (float*) (ws + 38273024);      //     16,384 B
    float*  qkbuf    = (float*) (ws + 38289408);      //     32,768 B
    int*    routes   = (int*)   (ws + 38322176);      //        512 B
    bf16_t* W1t      = (bf16_t*)(ws + 38322688);      //    327,680 B
    bf16_t* W2t      = (bf16_t*)(ws + 38650368);      //     65,536 B

    k_ln<<<512, 256, 0, stream>>>(x, gamma, beta, xn, partial);
    k_red1<<<64, 256, 0, stream>>>(partial, partial2);
    k_red2<<<16, 256, 0, stream>>>(partial2, repr);
    k_qk<<<64, 256, 0, stream>>>(repr, Wq, bq, Wk, bk, qkbuf);
    k_score<<<1, 256, 0, stream>>>(qkbuf, routes);
    k_prep<<<768, 256, 0, stream>>>(W1, W2, W1t, W2t);
    k_mlp<<<1024, 256, 0, stream>>>(x, xn, W1t, W2t, b1, b2, routes, out);
}